// Round 7
// baseline (2614.219 us; speedup 1.0000x reference)
//
#include <hip/hip_runtime.h>

#define N_NODES 10000
#define E_EDGES 32768
#define NEB (E_EDGES/64)   // 512 edge-blocks

typedef short bf16x8v __attribute__((ext_vector_type(8)));
typedef short bf16x4v __attribute__((ext_vector_type(4)));
typedef float f32x4   __attribute__((ext_vector_type(4)));
typedef float f32x2   __attribute__((ext_vector_type(2)));

__device__ __forceinline__ float bf2f(ushort u){
    union{ uint i; float f; } v; v.i = ((uint)u) << 16; return v.f;
}
__device__ __forceinline__ ushort f2bf(float f){
    union{ float f; uint i; } v; v.f = f;
    uint u = v.i;
    return (ushort)((u + 0x7fffu + ((u >> 16) & 1u)) >> 16);
}
__device__ __forceinline__ float ldf(float v){ return v; }
__device__ __forceinline__ float ldf(ushort v){ return bf2f(v); }

// packed 2xf32 FMA (VOP3P) — compiler never auto-emits for scalar code
__device__ __forceinline__ f32x2 pk_fma(f32x2 a, f32x2 b, f32x2 c){
    f32x2 d;
    asm("v_pk_fma_f32 %0, %1, %2, %3" : "=v"(d) : "v"(a), "v"(b), "v"(c));
    return d;
}

// async 16B global -> LDS (wave-uniform LDS base + lane*16)
__device__ __forceinline__ void async_copy16(const void* g, void* l){
    __builtin_amdgcn_global_load_lds(
        (const __attribute__((address_space(1))) void*)g,
        (__attribute__((address_space(3))) void*)l, 16, 0, 0);
}
// gfx9 s_waitcnt imm: vmcnt[3:0]=bits3:0, expcnt=bits6:4, lgkmcnt=bits11:8, vmcnt[5:4]=bits15:14
__device__ __forceinline__ void wait_vm0(){ __builtin_amdgcn_s_waitcnt(0x0F70); }  // vmcnt(0)

// ---------------------------------------------------------------------------
// edge_index normalization: detect int32 vs int64 layout, clamp, write int32.
// ---------------------------------------------------------------------------
__global__ void idx_detect(const int* __restrict__ w, int* __restrict__ flag){
    __shared__ int sh[256];
    int t = threadIdx.x;
    int o = 0;
    for (int i = 2*t + 1; i < 2*E_EDGES; i += 512) o |= w[i];
    sh[t] = o; __syncthreads();
    for (int s = 128; s; s >>= 1){ if (t < s) sh[t] |= sh[t+s]; __syncthreads(); }
    if (t == 0) *flag = sh[0];
}

__global__ void idx_norm(const int* __restrict__ w, const int* __restrict__ flag,
                         int* __restrict__ srcN, int* __restrict__ dstN){
    int e = blockIdx.x*256 + threadIdx.x;
    if (e >= E_EDGES) return;
    int s, d;
    if (*flag){ s = w[e];     d = w[E_EDGES + e]; }          // int32 layout
    else      { s = w[2*e];   d = w[2*E_EDGES + 2*e]; }      // int64 layout (low words)
    s = min(max(s, 0), N_NODES-1);
    d = min(max(d, 0), N_NODES-1);
    srcN[e] = s; dstN[e] = d;
}

// ---------------------------------------------------------------------------
// Fused per-edge-MLP GEMM + einsum + scatter-add.
//
// R7 (occupancy completion; R6 diagnostic proved REGISTER-cap: LDS 43.5 KB
// would fit 3 blocks/CU but occupancy stayed 23% — 124 VGPR + 64 AGPR acc
// = 188 > 512/3):
//  * conv2 KS=32 -> CH=2, kz=32: afA halves to 32 regs -> total ~156 <= 170
//    -> 3 waves/SIMD reachable.  __launch_bounds__(256, 3).
//  * depth-1 double-buffer retained (32 KB B region keeps LDS at 43.5 KB;
//    its exposed wait is what the 3rd wave covers).
//  * known costs: h-scale + per-block staging + atomics double with kz
//    (priced ~+10%); A-stage total unchanged (blocks x CH constant).
// ---------------------------------------------------------------------------
template<int K, int NI, int KS, typename TH>
__global__ __launch_bounds__(256, 3)
void gemm_msg(const float* __restrict__ ea4,
              const int* __restrict__ srcI, const int* __restrict__ dstI,
              const float* __restrict__ w1, const float* __restrict__ b1,
              const ushort* __restrict__ Bt, const float* __restrict__ b2,
              const TH* __restrict__ hsrc,
              float* __restrict__ nodesum)
{
    constexpr int CH = K / 64 / KS;   // K-chunks per block (A resident in regs), even
    constexpr int IP = NI / 2;        // i-pair passes (Ntile = 128)
    constexpr int NT = IP * CH;       // total tiles (>= 2)

    __shared__ __align__(16) ushort pool[16512];    // 33 KB: As(16K)/B-bufs(32K)/mr+b2s(33K)
    __shared__ __align__(16) ushort h_s[NI][68];
    __shared__ float ea_s[256];
    __shared__ int src_s[64];
    __shared__ int dst_s[64];

    const int bid  = blockIdx.x;
    const int eb   = bid % NEB;
    const int kz   = bid / NEB;
    const int t    = threadIdx.x;
    const int e0   = eb * 64;
    const int lane = t & 63;
    const int wv   = t >> 6;
    const int ng   = wv & 1;
    const int kg   = wv >> 1;
    const int q    = lane >> 4;
    const int ln   = lane & 15;

    if (t < 64){ src_s[t] = srcI[e0 + t]; dst_s[t] = dstI[e0 + t]; }
    ea_s[t] = ea4[e0 * 4 + t];
    __syncthreads();

    // stage h_s[i][row]
    if (NI == 64){
        int r = t >> 2, ig = t & 3;
        const ushort* hp = (const ushort*)hsrc + (size_t)src_s[r] * 64 + ig * 16;
        uint4 v0 = *(const uint4*)(hp);
        uint4 v1 = *(const uint4*)(hp + 8);
        const ushort* p0 = (const ushort*)&v0;
        const ushort* p1 = (const ushort*)&v1;
        #pragma unroll
        for (int ii = 0; ii < 8; ii++) h_s[ig*16 + ii    ][r] = p0[ii];
        #pragma unroll
        for (int ii = 0; ii < 8; ii++) h_s[ig*16 + 8 + ii][r] = p1[ii];
    } else {
        if (t < 64){
            const TH* hp = hsrc + (size_t)src_s[t] * NI;
            #pragma unroll
            for (int ii = 0; ii < NI; ii++) h_s[ii][t] = f2bf(ldf(hp[ii]));
        }
    }

    // stage all CH A-chunks into pool (on-the-fly edge MLP layer 1, pk-f32), swizzled
    #pragma unroll 1
    for (int kc = 0; kc < CH; kc++){
        int kcg = kz * CH + kc;
        #pragma unroll
        for (int s2 = 0; s2 < 2; s2++){
            int a = t + s2 * 256;
            int r = a >> 3, oct = a & 7;
            int k = kcg * 64 + oct * 8;
            f32x2 a2[4];
            float4 b0 = *(const float4*)(b1 + k);
            float4 b4 = *(const float4*)(b1 + k + 4);
            a2[0] = f32x2{b0.x, b0.y}; a2[1] = f32x2{b0.z, b0.w};
            a2[2] = f32x2{b4.x, b4.y}; a2[3] = f32x2{b4.z, b4.w};
            #pragma unroll
            for (int a4 = 0; a4 < 4; a4++){
                float4 w0 = *(const float4*)(w1 + (size_t)a4 * K + k);
                float4 w4 = *(const float4*)(w1 + (size_t)a4 * K + k + 4);
                float m = ea_s[r * 4 + a4];
                f32x2 mm = {m, m};
                a2[0] = pk_fma(mm, f32x2{w0.x, w0.y}, a2[0]);
                a2[1] = pk_fma(mm, f32x2{w0.z, w0.w}, a2[1]);
                a2[2] = pk_fma(mm, f32x2{w4.x, w4.y}, a2[2]);
                a2[3] = pk_fma(mm, f32x2{w4.z, w4.w}, a2[3]);
            }
            uint4 ov;
            ushort* po = (ushort*)&ov;
            #pragma unroll
            for (int j = 0; j < 8; j++) po[j] = f2bf(fmaxf(a2[j >> 1][j & 1], 0.f));
            *(uint4*)&pool[kc * 4096 + r * 64 + ((oct ^ (r & 7)) * 8)] = ov;
        }
    }
    __syncthreads();

    // hoist ALL A fragments to registers: afA[kc][ms]
    const int j0 = kg * 4 + q;
    bf16x8v afA[CH][4];
    #pragma unroll
    for (int kc = 0; kc < CH; kc++)
        #pragma unroll
        for (int ms = 0; ms < 4; ms++){
            int r = ms * 16 + ln;
            afA[kc][ms] = *(const bf16x8v*)&pool[kc * 4096 + r * 64 + ((j0 ^ (r & 7)) * 8)];
        }
    __syncthreads();   // pool is now free -> becomes wave-private B buffers

    // wave-private B buffers: TWO 4 KB per wave; tile g lives in buf (g&1) == (kc&1).
    // DMA perm: instr j, lane l fetches (row = j*16 + (l>>2), oct = (l&3)^((l>>3)&3));
    // reader slot (row r, oct o) = (r>>4)*64 + (r&15)*4 + (o^((r>>1)&3)):
    // all 8 16B-quads distinct per 8-lane reader group (conflict-free b128).
    const int rl4 = lane >> 2;
    const int ocp = (lane & 3) ^ ((lane >> 3) & 3);
    ushort* const lb0 = &pool[(wv * 2 + 0) * 2048];
    ushort* const lb1 = &pool[(wv * 2 + 1) * 2048];
    auto laneAddr = [&](int ip, int kc) -> const ushort* {
        return Bt + (size_t)(ip * 128 + ng * 64 + rl4) * K
                  + (size_t)(kz * CH + kc) * 64 + kg * 32 + ocp * 8;
    };
    auto issue = [&](const ushort* ga, ushort* lbase){
        #pragma unroll
        for (int j = 0; j < 4; j++)
            async_copy16(ga + (size_t)j * 16 * K, lbase + j * 512);
    };

    // prologue: issue tile 0 only (depth-1)
    issue(laneAddr(0, 0), lb0);

    // incrementally-advanced per-lane pointer for tile g+1 (starts at tile 1 = (0,1), CH>=2)
    const ushort* gp1 = laneAddr(0, 1);
    int kcn = 1;                          // kc-index of tile g+1
    constexpr size_t STRIDE_WRAP = (size_t)128 * K - (size_t)(CH - 1) * 64;  // ushorts

    f32x2 msgp[4][4][2];
    #pragma unroll
    for (int a = 0; a < 4; a++)
        #pragma unroll
        for (int b = 0; b < 4; b++){
            msgp[a][b][0] = f32x2{0.f, 0.f};
            msgp[a][b][1] = f32x2{0.f, 0.f};
        }

    const f32x4 fzero = {0.f, 0.f, 0.f, 0.f};
    const int bslot = (ln * 4 + (q ^ ((ln >> 1) & 3))) * 8;   // ushort offset of lane's b128
    int g = 0;
    #pragma unroll 1
    for (int ip = 0; ip < IP; ip++){
        f32x4 acc[4][4];
        #pragma unroll
        for (int kc = 0; kc < CH; kc++, g++){
            ushort* const bcur = ((kc & 1) == 0) ? lb0 : lb1;   // tile g
            ushort* const bnxt = ((kc & 1) == 0) ? lb1 : lb0;   // tile g+1 dest

            wait_vm0();                         // tile g's DMA landed
            __builtin_amdgcn_sched_barrier(0);  // pin: nothing crosses the wait

            // issue tile g+1 (flies across this tile's reads + MFMA)
            if (g + 1 < NT){
                issue(gp1, bnxt);
                gp1 += (kcn == CH - 1) ? STRIDE_WRAP : (size_t)64;
                kcn  = (kcn == CH - 1) ? 0 : kcn + 1;
            }

            bf16x8v bfr[4];
            #pragma unroll
            for (int ns = 0; ns < 4; ns++)
                bfr[ns] = *(const bf16x8v*)&bcur[ns * 512 + bslot];

            __builtin_amdgcn_s_setprio(1);
            #pragma unroll
            for (int ms = 0; ms < 4; ms++)
                #pragma unroll
                for (int ns = 0; ns < 4; ns++)
                    acc[ms][ns] = __builtin_amdgcn_mfma_f32_16x16x32_bf16(
                        afA[kc][ms], bfr[ns], (kc == 0) ? fzero : acc[ms][ns], 0, 0, 0);
            __builtin_amdgcn_s_setprio(0);
        }
        // h-scale epilogue (packed f32), once per i-pair
        int i2 = ip * 2 + ng;
        #pragma unroll
        for (int ms = 0; ms < 4; ms++){
            bf16x4v hb = *(const bf16x4v*)&h_s[i2][ms * 16 + q * 4];
            f32x2 h01, h23;
            h01[0] = bf2f((ushort)hb[0]); h01[1] = bf2f((ushort)hb[1]);
            h23[0] = bf2f((ushort)hb[2]); h23[1] = bf2f((ushort)hb[3]);
            #pragma unroll
            for (int ns = 0; ns < 4; ns++){
                f32x2 lo = __builtin_shufflevector(acc[ms][ns], acc[ms][ns], 0, 1);
                f32x2 hi = __builtin_shufflevector(acc[ms][ns], acc[ms][ns], 2, 3);
                msgp[ms][ns][0] = pk_fma(h01, lo, msgp[ms][ns][0]);
                msgp[ms][ns][1] = pk_fma(h23, hi, msgp[ms][ns][1]);
            }
        }
    }

    // reduce the 4 waves' msg partials in LDS (reuse pool), add b2 (kz==0), scatter
    __syncthreads();
    float* mr  = (float*)&pool[0];         // [64][65] f32 = 16,640 B
    float* b2s = (float*)&pool[0] + 4160;  // b2 staged: 16,384 B (ends 33,024 B = pool)
    if (kz == 0){
        for (int i = t; i < NI * 64; i += 256) b2s[i] = b2[i];
    }
    #pragma unroll 1
    for (int r4 = 0; r4 < 4; r4++){
        if (wv == r4){
            #pragma unroll
            for (int ms = 0; ms < 4; ms++)
                #pragma unroll
                for (int ns = 0; ns < 4; ns++)
                    #pragma unroll
                    for (int j = 0; j < 4; j++){
                        int row = ms * 16 + q * 4 + j, col = ns * 16 + ln;
                        float v = msgp[ms][ns][j >> 1][j & 1];
                        if (r4 == 0) mr[row * 65 + col]  = v;
                        else         mr[row * 65 + col] += v;
                    }
        }
        __syncthreads();
    }
    #pragma unroll 1
    for (int s2 = 0; s2 < 16; s2++){
        int a = t + s2 * 256;
        int row = a >> 6, o = a & 63;
        float v = mr[row * 65 + o];
        if (kz == 0){
            #pragma unroll 4
            for (int ii = 0; ii < NI; ii++)
                v += bf2f(h_s[ii][row]) * b2s[ii * 64 + o];
        }
        atomicAdd(nodesum + (size_t)dst_s[row] * 64 + o, v);
    }
}

// ---------------------------------------------------------------------------
__global__ void transpose_f2b(const float* __restrict__ in, ushort* __restrict__ out, int D){
    __shared__ float tl[32][33];
    int bx = blockIdx.x, by = blockIdx.y;
    int tx = threadIdx.x, ty = threadIdx.y;
    #pragma unroll
    for (int r = 0; r < 4; r++)
        tl[ty + 8*r][tx] = in[(size_t)(by*32 + ty + 8*r) * D + bx*32 + tx];
    __syncthreads();
    #pragma unroll
    for (int r = 0; r < 4; r++)
        out[(size_t)(bx*32 + ty + 8*r) * D + by*32 + tx] = f2bf(tl[tx][ty + 8*r]);
}

__global__ void count_k(const int* __restrict__ dstI, float* __restrict__ cnt){
    int e = blockIdx.x * 256 + threadIdx.x;
    if (e < E_EDGES) atomicAdd(cnt + dstI[e], 1.f);
}

template<int NIn, typename TI>
__global__ void node_k(const float* __restrict__ ns_, const float* __restrict__ cnt,
                       const TI* __restrict__ xin, const float* __restrict__ root,
                       const float* __restrict__ bias,
                       ushort* __restrict__ hb, float* __restrict__ hf, int Nn)
{
    int idx = blockIdx.x * 256 + threadIdx.x;
    if (idx >= Nn * 64) return;
    int n = idx >> 6, o = idx & 63;
    float c = cnt[n];
    float inv = c > 1.f ? 1.f / c : 1.f;
    float s = ns_[idx] * inv + bias[o];
    #pragma unroll
    for (int i = 0; i < NIn; i++)
        s += ldf(xin[(size_t)n * NIn + i]) * root[i * 64 + o];
    s = fmaxf(s, 0.f);
    if (hb) hb[idx] = f2bf(s);
    else    hf[idx] = s;
}

// outputs FLOAT32: [E] prob | [E,3] types | [E] src | [E] dst
__global__ void edge_out_k(const float* __restrict__ h2, const int* __restrict__ srcI,
                           const int* __restrict__ dstI, const float* __restrict__ ea,
                           const float* __restrict__ fcw, const float* __restrict__ fcb,
                           float* __restrict__ out)
{
    __shared__ float fw[396];
    __shared__ float fb[3];
    int t = threadIdx.x;
    for (int i = t; i < 396; i += 256) fw[i] = fcw[i];
    if (t < 3) fb[t] = fcb[t];
    __syncthreads();
    int e = blockIdx.x * 256 + t;
    int s = srcI[e], d = dstI[e];
    const float* hs = h2 + (size_t)s * 64;
    const float* hd = h2 + (size_t)d * 64;
    float dot = 0.f, l0 = fb[0], l1 = fb[1], l2 = fb[2];
    #pragma unroll 8
    for (int c = 0; c < 64; c++){
        float a = hs[c], b = hd[c];
        dot += a * b;
        l0 += a * fw[c*3+0] + b * fw[(64+c)*3+0];
        l1 += a * fw[c*3+1] + b * fw[(64+c)*3+1];
        l2 += a * fw[c*3+2] + b * fw[(64+c)*3+2];
    }
    #pragma unroll
    for (int a4 = 0; a4 < 4; a4++){
        float v = ea[e*4 + a4];
        l0 += v * fw[(128+a4)*3+0];
        l1 += v * fw[(128+a4)*3+1];
        l2 += v * fw[(128+a4)*3+2];
    }
    float prob = 1.f / (1.f + __expf(-dot));
    float m  = fmaxf(l0, fmaxf(l1, l2));
    float x0 = __expf(l0 - m), x1 = __expf(l1 - m), x2 = __expf(l2 - m);
    float inv = 1.f / (x0 + x1 + x2);
    out[e]                  = prob;
    out[E_EDGES + 3*e + 0]  = x0 * inv;
    out[E_EDGES + 3*e + 1]  = x1 * inv;
    out[E_EDGES + 3*e + 2]  = x2 * inv;
    out[4*E_EDGES + e]      = (float)s;
    out[5*E_EDGES + e]      = (float)d;
}

// ---------------------------------------------------------------------------
extern "C" void kernel_launch(void* const* d_in, const int* in_sizes, int n_in,
                              void* d_out, int out_size, void* d_ws, size_t ws_size,
                              hipStream_t stream)
{
    const float* x     = (const float*)d_in[0];
    const int*   ei    = (const int*)  d_in[1];
    const float* ea    = (const float*)d_in[2];
    const float* e1w1  = (const float*)d_in[3];
    const float* e1b1  = (const float*)d_in[4];
    const float* e1w2  = (const float*)d_in[5];
    const float* e1b2  = (const float*)d_in[6];
    const float* root1 = (const float*)d_in[7];
    const float* bias1 = (const float*)d_in[8];
    const float* e2w1  = (const float*)d_in[9];
    const float* e2b1  = (const float*)d_in[10];
    const float* e2w2  = (const float*)d_in[11];
    const float* e2b2  = (const float*)d_in[12];
    const float* root2 = (const float*)d_in[13];
    const float* bias2 = (const float*)d_in[14];
    const float* fcw   = (const float*)d_in[15];
    const float* fcb   = (const float*)d_in[16];

    char* ws = (char*)d_ws;
    float*  ns1  = (float*) (ws + 0);          // [N,64] f32   2,560,000 B
    float*  ns2  = (float*) (ws + 2560000);    // [N,64] f32   2,560,000 B
    float*  cnt  = (float*) (ws + 5120000);    // [N] f32         40,000 B
    int*    flag = (int*)   (ws + 5160000);    // 4 B (+pad)
    int*    srcN = (int*)   (ws + 5160064);    // [E] int32     131,072 B
    int*    dstN = (int*)   (ws + 5291136);    // [E] int32     131,072 B
    ushort* h1   = (ushort*)(ws + 5422208);    // [N,64] bf16 1,280,000 B
    float*  h2   = (float*) (ws + 6702208);    // [N,64] f32  2,560,000 B
    ushort* B1t  = (ushort*)(ws + 9262208);    // e1w2^T bf16 [384,384]
    ushort* B2t  = (ushort*)(ws + 9557120);    // e2w2^T bf16 [4096,4096] -> ends 43,111,552

    hipMemsetAsync(d_ws, 0, 5160064, stream);   // zero ns1, ns2, cnt, flag

    idx_detect<<<1, 256, 0, stream>>>(ei, flag);
    idx_norm<<<128, 256, 0, stream>>>(ei, flag, srcN, dstN);

    transpose_f2b<<<dim3(12, 12),  dim3(32, 8), 0, stream>>>(e1w2, B1t, 384);
    transpose_f2b<<<dim3(128,128), dim3(32, 8), 0, stream>>>(e2w2, B2t, 4096);
    count_k<<<128, 256, 0, stream>>>(dstN, cnt);

    // small conv1: K=384, KS=3 -> CH=2, IP=3
    gemm_msg<384, 6, 3, float><<<NEB*3, 256, 0, stream>>>(ea, srcN, dstN, e1w1, e1b1, B1t, e1b2, x, ns1);
    node_k<6, float><<<2500, 256, 0, stream>>>(ns1, cnt, x, root1, bias1, h1, nullptr, N_NODES);

    // big conv2: K=4096, KS=32 -> CH=2, IP=32, kz=32 (regs ~156 -> 3 waves/SIMD target)
    gemm_msg<4096, 64, 32, ushort><<<NEB*32, 256, 0, stream>>>(ea, srcN, dstN, e2w1, e2b1, B2t, e2b2, h1, ns2);
    node_k<64, ushort><<<2500, 256, 0, stream>>>(ns2, cnt, h1, root2, bias2, nullptr, h2, N_NODES);

    edge_out_k<<<128, 256, 0, stream>>>(h2, srcN, dstN, ea, fcw, fcb, (float*)d_out);
}

// Round 9
// 1417.278 us; speedup vs baseline: 1.8445x; 1.8445x over previous
//
#include <hip/hip_runtime.h>

#define N_NODES 10000
#define E_EDGES 32768
#define NEB (E_EDGES/64)   // 512 edge-blocks

typedef short bf16x8v __attribute__((ext_vector_type(8)));
typedef short bf16x4v __attribute__((ext_vector_type(4)));
typedef float f32x4   __attribute__((ext_vector_type(4)));
typedef float f32x2   __attribute__((ext_vector_type(2)));

__device__ __forceinline__ float bf2f(ushort u){
    union{ uint i; float f; } v; v.i = ((uint)u) << 16; return v.f;
}
__device__ __forceinline__ ushort f2bf(float f){
    union{ float f; uint i; } v; v.f = f;
    uint u = v.i;
    return (ushort)((u + 0x7fffu + ((u >> 16) & 1u)) >> 16);
}
__device__ __forceinline__ float ldf(float v){ return v; }
__device__ __forceinline__ float ldf(ushort v){ return bf2f(v); }

// packed 2xf32 FMA (VOP3P) — compiler never auto-emits for scalar code
__device__ __forceinline__ f32x2 pk_fma(f32x2 a, f32x2 b, f32x2 c){
    f32x2 d;
    asm("v_pk_fma_f32 %0, %1, %2, %3" : "=v"(d) : "v"(a), "v"(b), "v"(c));
    return d;
}

// async 16B global -> LDS (wave-uniform LDS base + lane*16)
__device__ __forceinline__ void async_copy16(const void* g, void* l){
    __builtin_amdgcn_global_load_lds(
        (const __attribute__((address_space(1))) void*)g,
        (__attribute__((address_space(3))) void*)l, 16, 0, 0);
}
// gfx9 s_waitcnt imm: vmcnt[3:0]=bits3:0, expcnt=bits6:4, lgkmcnt=bits11:8, vmcnt[5:4]=bits15:14
__device__ __forceinline__ void wait_vm0(){ __builtin_amdgcn_s_waitcnt(0x0F70); }  // vmcnt(0)
__device__ __forceinline__ void wait_vm4(){ __builtin_amdgcn_s_waitcnt(0x0F74); }  // vmcnt(4)

// ---------------------------------------------------------------------------
// edge_index normalization: detect int32 vs int64 layout, clamp, write int32.
// ---------------------------------------------------------------------------
__global__ void idx_detect(const int* __restrict__ w, int* __restrict__ flag){
    __shared__ int sh[256];
    int t = threadIdx.x;
    int o = 0;
    for (int i = 2*t + 1; i < 2*E_EDGES; i += 512) o |= w[i];
    sh[t] = o; __syncthreads();
    for (int s = 128; s; s >>= 1){ if (t < s) sh[t] |= sh[t+s]; __syncthreads(); }
    if (t == 0) *flag = sh[0];
}

__global__ void idx_norm(const int* __restrict__ w, const int* __restrict__ flag,
                         int* __restrict__ srcN, int* __restrict__ dstN){
    int e = blockIdx.x*256 + threadIdx.x;
    if (e >= E_EDGES) return;
    int s, d;
    if (*flag){ s = w[e];     d = w[E_EDGES + e]; }          // int32 layout
    else      { s = w[2*e];   d = w[2*E_EDGES + 2*e]; }      // int64 layout (low words)
    s = min(max(s, 0), N_NODES-1);
    d = min(max(d, 0), N_NODES-1);
    srcN[e] = s; dstN[e] = d;
}

// ---------------------------------------------------------------------------
// Fused per-edge-MLP GEMM + einsum + scatter-add.  R9 = R4 resubmit (R8's
// bench was an infra failure; source identical to the measured 1289 us /
// MfmaUtil 39% floor kernel).
//
// Session map (R1-R7): bank-conflict fix (R1, conflicts -86%, dur flat),
// LDS-latency read-ahead (R2, -3%), 128-edge retile (R3, flat), VALU-stream
// cuts (R4, -15% <- the real lever), 32x32 MFMA (R5, -10%: conflict
// regression), depth-1 LDS cut (R6: proved REG-cap, depth-1 costs 10%),
// CH=2 for 3 waves/SIMD (R7: occupancy +50% but kz-doubling fixed costs
// +100%).  Conclusion: 2-wave/SIMD latency-chain equilibrium; MFMA 39 +
// VALU 31 + wait ~30 sum to the round; every weight-shift attempt <= 0.
//
// R4 structure: 64-edge blocks, kz=16, 16x16x32 MFMA, depth-2 wave-private
// triple-buffer DMA (wait vmcnt(4), never 0 except final), conflict-free
// B swizzle, pk-f32 h-scale + A-stage, ptr-incr DMA addressing, b2 via LDS.
// ---------------------------------------------------------------------------
template<int K, int NI, int KS, typename TH>
__global__ __launch_bounds__(256, 2)
void gemm_msg(const float* __restrict__ ea4,
              const int* __restrict__ srcI, const int* __restrict__ dstI,
              const float* __restrict__ w1, const float* __restrict__ b1,
              const ushort* __restrict__ Bt, const float* __restrict__ b2,
              const TH* __restrict__ hsrc,
              float* __restrict__ nodesum)
{
    constexpr int CH = K / 64 / KS;   // K-chunks per block (A resident in regs)
    constexpr int IP = NI / 2;        // i-pair passes (Ntile = 128)
    constexpr int NT = IP * CH;       // total tiles (>= 2)

    __shared__ __align__(16) ushort pool[24576];    // 48 KB: As / B-bufs / mr+b2s
    __shared__ __align__(16) ushort h_s[NI][68];
    __shared__ float ea_s[256];
    __shared__ int src_s[64];
    __shared__ int dst_s[64];

    const int bid  = blockIdx.x;
    const int eb   = bid % NEB;
    const int kz   = bid / NEB;
    const int t    = threadIdx.x;
    const int e0   = eb * 64;
    const int lane = t & 63;
    const int wv   = t >> 6;
    const int ng   = wv & 1;
    const int kg   = wv >> 1;
    const int q    = lane >> 4;
    const int ln   = lane & 15;

    if (t < 64){ src_s[t] = srcI[e0 + t]; dst_s[t] = dstI[e0 + t]; }
    ea_s[t] = ea4[e0 * 4 + t];
    __syncthreads();

    // stage h_s[i][row]
    if (NI == 64){
        int r = t >> 2, ig = t & 3;
        const ushort* hp = (const ushort*)hsrc + (size_t)src_s[r] * 64 + ig * 16;
        uint4 v0 = *(const uint4*)(hp);
        uint4 v1 = *(const uint4*)(hp + 8);
        const ushort* p0 = (const ushort*)&v0;
        const ushort* p1 = (const ushort*)&v1;
        #pragma unroll
        for (int ii = 0; ii < 8; ii++) h_s[ig*16 + ii    ][r] = p0[ii];
        #pragma unroll
        for (int ii = 0; ii < 8; ii++) h_s[ig*16 + 8 + ii][r] = p1[ii];
    } else {
        if (t < 64){
            const TH* hp = hsrc + (size_t)src_s[t] * NI;
            #pragma unroll
            for (int ii = 0; ii < NI; ii++) h_s[ii][t] = f2bf(ldf(hp[ii]));
        }
    }

    // stage all CH A-chunks into pool (on-the-fly edge MLP layer 1, pk-f32), swizzled
    #pragma unroll 1
    for (int kc = 0; kc < CH; kc++){
        int kcg = kz * CH + kc;
        #pragma unroll
        for (int s2 = 0; s2 < 2; s2++){
            int a = t + s2 * 256;
            int r = a >> 3, oct = a & 7;
            int k = kcg * 64 + oct * 8;
            f32x2 a2[4];
            float4 b0 = *(const float4*)(b1 + k);
            float4 b4 = *(const float4*)(b1 + k + 4);
            a2[0] = f32x2{b0.x, b0.y}; a2[1] = f32x2{b0.z, b0.w};
            a2[2] = f32x2{b4.x, b4.y}; a2[3] = f32x2{b4.z, b4.w};
            #pragma unroll
            for (int a4 = 0; a4 < 4; a4++){
                float4 w0 = *(const float4*)(w1 + (size_t)a4 * K + k);
                float4 w4 = *(const float4*)(w1 + (size_t)a4 * K + k + 4);
                float m = ea_s[r * 4 + a4];
                f32x2 mm = {m, m};
                a2[0] = pk_fma(mm, f32x2{w0.x, w0.y}, a2[0]);
                a2[1] = pk_fma(mm, f32x2{w0.z, w0.w}, a2[1]);
                a2[2] = pk_fma(mm, f32x2{w4.x, w4.y}, a2[2]);
                a2[3] = pk_fma(mm, f32x2{w4.z, w4.w}, a2[3]);
            }
            uint4 ov;
            ushort* po = (ushort*)&ov;
            #pragma unroll
            for (int j = 0; j < 8; j++) po[j] = f2bf(fmaxf(a2[j >> 1][j & 1], 0.f));
            *(uint4*)&pool[kc * 4096 + r * 64 + ((oct ^ (r & 7)) * 8)] = ov;
        }
    }
    __syncthreads();

    // hoist ALL A fragments to registers: afA[kc][ms]
    const int j0 = kg * 4 + q;
    bf16x8v afA[CH][4];
    #pragma unroll
    for (int kc = 0; kc < CH; kc++)
        #pragma unroll
        for (int ms = 0; ms < 4; ms++){
            int r = ms * 16 + ln;
            afA[kc][ms] = *(const bf16x8v*)&pool[kc * 4096 + r * 64 + ((j0 ^ (r & 7)) * 8)];
        }
    __syncthreads();   // pool is now free -> becomes wave-private B buffers

    // wave-private B buffer: pool[(wv*3+buf)*2048 .. +2048) ushorts, buf in {0,1,2}
    // DMA perm: lane l fetches (row = j*16 + (l>>2), oct = (l&3)^((l>>3)&3));
    // reader slot (row r, oct o) = (r>>4)*64 + (r&15)*4 + (o^((r>>1)&3)):
    // all 8 16B-quads distinct per 8-lane reader group (conflict-free b128).
    const int rl4 = lane >> 2;
    const int ocp = (lane & 3) ^ ((lane >> 3) & 3);
    auto laneAddr = [&](int ip, int kc) -> const ushort* {
        return Bt + (size_t)(ip * 128 + ng * 64 + rl4) * K
                  + (size_t)(kz * CH + kc) * 64 + kg * 32 + ocp * 8;
    };
    auto issue = [&](const ushort* ga, ushort* lbase){
        #pragma unroll
        for (int j = 0; j < 4; j++)
            async_copy16(ga + (size_t)j * 16 * K, lbase + j * 512);
    };

    // prologue: issue tiles 0 and 1 (depth-2); CH >= 2 so tile1 = (ip0, kc1)
    issue(laneAddr(0, 0), &pool[(wv * 3 + 0) * 2048]);
    issue(laneAddr(0, 1), &pool[(wv * 3 + 1) * 2048]);

    // incrementally-advanced per-lane pointer for tile g+2
    const ushort* gp2 = laneAddr(2 / CH, 2 % CH);
    int kcn = 2 % CH;                     // kc-index of tile g+2
    constexpr size_t STRIDE_WRAP = (size_t)128 * K - (size_t)(CH - 1) * 64;  // ushorts

    f32x2 msgp[4][4][2];
    #pragma unroll
    for (int a = 0; a < 4; a++)
        #pragma unroll
        for (int b = 0; b < 4; b++){
            msgp[a][b][0] = f32x2{0.f, 0.f};
            msgp[a][b][1] = f32x2{0.f, 0.f};
        }

    const f32x4 fzero = {0.f, 0.f, 0.f, 0.f};
    const int bslot = (ln * 4 + (q ^ ((ln >> 1) & 3))) * 8;   // ushort offset of lane's b128
    int g = 0;
    int bufc = 0;   // consume buffer
    int bufi = 2;   // issue buffer (for tile g+2)
    #pragma unroll 1
    for (int ip = 0; ip < IP; ip++){
        f32x4 acc[4][4];
        #pragma unroll
        for (int kc = 0; kc < CH; kc++, g++){
            const ushort* bwc = &pool[(wv * 3 + bufc) * 2048];

            if (g < NT - 1) wait_vm4();   // tile g landed; g+1 stays in flight
            else            wait_vm0();   // final tile

            bf16x8v bfr[4];
            #pragma unroll
            for (int ns = 0; ns < 4; ns++)
                bfr[ns] = *(const bf16x8v*)&bwc[ns * 512 + bslot];

            // prefetch tile g+2 (flies across the next full iteration)
            if (g + 2 < NT){
                issue(gp2, &pool[(wv * 3 + bufi) * 2048]);
                gp2 += (kcn == CH - 1) ? STRIDE_WRAP : (size_t)64;
                kcn  = (kcn == CH - 1) ? 0 : kcn + 1;
            }

            __builtin_amdgcn_s_setprio(1);
            #pragma unroll
            for (int ms = 0; ms < 4; ms++)
                #pragma unroll
                for (int ns = 0; ns < 4; ns++)
                    acc[ms][ns] = __builtin_amdgcn_mfma_f32_16x16x32_bf16(
                        afA[kc][ms], bfr[ns], (kc == 0) ? fzero : acc[ms][ns], 0, 0, 0);
            __builtin_amdgcn_s_setprio(0);

            bufc = (bufc == 2) ? 0 : bufc + 1;
            bufi = (bufi == 2) ? 0 : bufi + 1;
        }
        // h-scale epilogue (packed f32), once per i-pair
        int i2 = ip * 2 + ng;
        #pragma unroll
        for (int ms = 0; ms < 4; ms++){
            bf16x4v hb = *(const bf16x4v*)&h_s[i2][ms * 16 + q * 4];
            f32x2 h01, h23;
            h01[0] = bf2f((ushort)hb[0]); h01[1] = bf2f((ushort)hb[1]);
            h23[0] = bf2f((ushort)hb[2]); h23[1] = bf2f((ushort)hb[3]);
            #pragma unroll
            for (int ns = 0; ns < 4; ns++){
                f32x2 lo = __builtin_shufflevector(acc[ms][ns], acc[ms][ns], 0, 1);
                f32x2 hi = __builtin_shufflevector(acc[ms][ns], acc[ms][ns], 2, 3);
                msgp[ms][ns][0] = pk_fma(h01, lo, msgp[ms][ns][0]);
                msgp[ms][ns][1] = pk_fma(h23, hi, msgp[ms][ns][1]);
            }
        }
    }

    // reduce the 4 waves' msg partials in LDS (reuse pool), add b2 (kz==0), scatter
    __syncthreads();
    float* mr  = (float*)&pool[0];      // [64][65] f32 = 16.6 KB
    float* b2s = (float*)&pool[0] + 4224;  // b2 staged: up to 16 KB (ends 33,280 B < 48 KB)
    if (kz == 0){
        for (int i = t; i < NI * 64; i += 256) b2s[i] = b2[i];
    }
    #pragma unroll 1
    for (int r4 = 0; r4 < 4; r4++){
        if (wv == r4){
            #pragma unroll
            for (int ms = 0; ms < 4; ms++)
                #pragma unroll
                for (int ns = 0; ns < 4; ns++)
                    #pragma unroll
                    for (int j = 0; j < 4; j++){
                        int row = ms * 16 + q * 4 + j, col = ns * 16 + ln;
                        float v = msgp[ms][ns][j >> 1][j & 1];
                        if (r4 == 0) mr[row * 65 + col]  = v;
                        else         mr[row * 65 + col] += v;
                    }
        }
        __syncthreads();
    }
    #pragma unroll 1
    for (int s2 = 0; s2 < 16; s2++){
        int a = t + s2 * 256;
        int row = a >> 6, o = a & 63;
        float v = mr[row * 65 + o];
        if (kz == 0){
            #pragma unroll 4
            for (int ii = 0; ii < NI; ii++)
                v += bf2f(h_s[ii][row]) * b2s[ii * 64 + o];
        }
        atomicAdd(nodesum + (size_t)dst_s[row] * 64 + o, v);
    }
}

// ---------------------------------------------------------------------------
__global__ void transpose_f2b(const float* __restrict__ in, ushort* __restrict__ out, int D){
    __shared__ float tl[32][33];
    int bx = blockIdx.x, by = blockIdx.y;
    int tx = threadIdx.x, ty = threadIdx.y;
    #pragma unroll
    for (int r = 0; r < 4; r++)
        tl[ty + 8*r][tx] = in[(size_t)(by*32 + ty + 8*r) * D + bx*32 + tx];
    __syncthreads();
    #pragma unroll
    for (int r = 0; r < 4; r++)
        out[(size_t)(bx*32 + ty + 8*r) * D + by*32 + tx] = f2bf(tl[tx][ty + 8*r]);
}

__global__ void count_k(const int* __restrict__ dstI, float* __restrict__ cnt){
    int e = blockIdx.x * 256 + threadIdx.x;
    if (e < E_EDGES) atomicAdd(cnt + dstI[e], 1.f);
}

template<int NIn, typename TI>
__global__ void node_k(const float* __restrict__ ns_, const float* __restrict__ cnt,
                       const TI* __restrict__ xin, const float* __restrict__ root,
                       const float* __restrict__ bias,
                       ushort* __restrict__ hb, float* __restrict__ hf, int Nn)
{
    int idx = blockIdx.x * 256 + threadIdx.x;
    if (idx >= Nn * 64) return;
    int n = idx >> 6, o = idx & 63;
    float c = cnt[n];
    float inv = c > 1.f ? 1.f / c : 1.f;
    float s = ns_[idx] * inv + bias[o];
    #pragma unroll
    for (int i = 0; i < NIn; i++)
        s += ldf(xin[(size_t)n * NIn + i]) * root[i * 64 + o];
    s = fmaxf(s, 0.f);
    if (hb) hb[idx] = f2bf(s);
    else    hf[idx] = s;
}

// outputs FLOAT32: [E] prob | [E,3] types | [E] src | [E] dst
__global__ void edge_out_k(const float* __restrict__ h2, const int* __restrict__ srcI,
                           const int* __restrict__ dstI, const float* __restrict__ ea,
                           const float* __restrict__ fcw, const float* __restrict__ fcb,
                           float* __restrict__ out)
{
    __shared__ float fw[396];
    __shared__ float fb[3];
    int t = threadIdx.x;
    for (int i = t; i < 396; i += 256) fw[i] = fcw[i];
    if (t < 3) fb[t] = fcb[t];
    __syncthreads();
    int e = blockIdx.x * 256 + t;
    int s = srcI[e], d = dstI[e];
    const float* hs = h2 + (size_t)s * 64;
    const float* hd = h2 + (size_t)d * 64;
    float dot = 0.f, l0 = fb[0], l1 = fb[1], l2 = fb[2];
    #pragma unroll 8
    for (int c = 0; c < 64; c++){
        float a = hs[c], b = hd[c];
        dot += a * b;
        l0 += a * fw[c*3+0] + b * fw[(64+c)*3+0];
        l1 += a * fw[c*3+1] + b * fw[(64+c)*3+1];
        l2 += a * fw[c*3+2] + b * fw[(64+c)*3+2];
    }
    #pragma unroll
    for (int a4 = 0; a4 < 4; a4++){
        float v = ea[e*4 + a4];
        l0 += v * fw[(128+a4)*3+0];
        l1 += v * fw[(128+a4)*3+1];
        l2 += v * fw[(128+a4)*3+2];
    }
    float prob = 1.f / (1.f + __expf(-dot));
    float m  = fmaxf(l0, fmaxf(l1, l2));
    float x0 = __expf(l0 - m), x1 = __expf(l1 - m), x2 = __expf(l2 - m);
    float inv = 1.f / (x0 + x1 + x2);
    out[e]                  = prob;
    out[E_EDGES + 3*e + 0]  = x0 * inv;
    out[E_EDGES + 3*e + 1]  = x1 * inv;
    out[E_EDGES + 3*e + 2]  = x2 * inv;
    out[4*E_EDGES + e]      = (float)s;
    out[5*E_EDGES + e]      = (float)d;
}

// ---------------------------------------------------------------------------
extern "C" void kernel_launch(void* const* d_in, const int* in_sizes, int n_in,
                              void* d_out, int out_size, void* d_ws, size_t ws_size,
                              hipStream_t stream)
{
    const float* x     = (const float*)d_in[0];
    const int*   ei    = (const int*)  d_in[1];
    const float* ea    = (const float*)d_in[2];
    const float* e1w1  = (const float*)d_in[3];
    const float* e1b1  = (const float*)d_in[4];
    const float* e1w2  = (const float*)d_in[5];
    const float* e1b2  = (const float*)d_in[6];
    const float* root1 = (const float*)d_in[7];
    const float* bias1 = (const float*)d_in[8];
    const float* e2w1  = (const float*)d_in[9];
    const float* e2b1  = (const float*)d_in[10];
    const float* e2w2  = (const float*)d_in[11];
    const float* e2b2  = (const float*)d_in[12];
    const float* root2 = (const float*)d_in[13];
    const float* bias2 = (const float*)d_in[14];
    const float* fcw   = (const float*)d_in[15];
    const float* fcb   = (const float*)d_in[16];

    char* ws = (char*)d_ws;
    float*  ns1  = (float*) (ws + 0);          // [N,64] f32   2,560,000 B
    float*  ns2  = (float*) (ws + 2560000);    // [N,64] f32   2,560,000 B
    float*  cnt  = (float*) (ws + 5120000);    // [N] f32         40,000 B
    int*    flag = (int*)   (ws + 5160000);    // 4 B (+pad)
    int*    srcN = (int*)   (ws + 5160064);    // [E] int32     131,072 B
    int*    dstN = (int*)   (ws + 5291136);    // [E] int32     131,072 B
    ushort* h1   = (ushort*)(ws + 5422208);    // [N,64] bf16 1,280,000 B
    float*  h2   = (float*) (ws + 6702208);    // [N,64] f32  2,560,000 B
    ushort* B1t  = (ushort*)(ws + 9262208);    // e1w2^T bf16 [384,384]
    ushort* B2t  = (ushort*)(ws + 9557120);    // e2w2^T bf16 [4096,4096] -> ends 43,111,552

    hipMemsetAsync(d_ws, 0, 5160064, stream);   // zero ns1, ns2, cnt, flag

    idx_detect<<<1, 256, 0, stream>>>(ei, flag);
    idx_norm<<<128, 256, 0, stream>>>(ei, flag, srcN, dstN);

    transpose_f2b<<<dim3(12, 12),  dim3(32, 8), 0, stream>>>(e1w2, B1t, 384);
    transpose_f2b<<<dim3(128,128), dim3(32, 8), 0, stream>>>(e2w2, B2t, 4096);
    count_k<<<128, 256, 0, stream>>>(dstN, cnt);

    // small conv1: K=384, KS=3 -> CH=2, IP=3
    gemm_msg<384, 6, 3, float><<<NEB*3, 256, 0, stream>>>(ea, srcN, dstN, e1w1, e1b1, B1t, e1b2, x, ns1);
    node_k<6, float><<<2500, 256, 0, stream>>>(ns1, cnt, x, root1, bias1, h1, nullptr, N_NODES);

    // big conv2: K=4096, KS=16 -> CH=4, IP=32 (kz=16; pk-f32 h-scale, ptr-incr DMA)
    gemm_msg<4096, 64, 16, ushort><<<NEB*16, 256, 0, stream>>>(ea, srcN, dstN, e2w1, e2b1, B2t, e2b2, h1, ns2);
    node_k<64, ushort><<<2500, 256, 0, stream>>>(ns2, cnt, h1, root2, bias2, nullptr, h2, N_NODES);

    edge_out_k<<<128, 256, 0, stream>>>(h2, srcN, dstN, ea, fcw, fcb, (float*)d_out);
}

// Round 10
// 1240.475 us; speedup vs baseline: 2.1074x; 1.1425x over previous
//
#include <hip/hip_runtime.h>

#define N_NODES 10000
#define E_EDGES 32768
#define NEB (E_EDGES/64)   // 512 edge-blocks

typedef short bf16x8v __attribute__((ext_vector_type(8)));
typedef short bf16x4v __attribute__((ext_vector_type(4)));
typedef float f32x4   __attribute__((ext_vector_type(4)));
typedef float f32x2   __attribute__((ext_vector_type(2)));

__device__ __forceinline__ float bf2f(ushort u){
    union{ uint i; float f; } v; v.i = ((uint)u) << 16; return v.f;
}
__device__ __forceinline__ ushort f2bf(float f){
    union{ float f; uint i; } v; v.f = f;
    uint u = v.i;
    return (ushort)((u + 0x7fffu + ((u >> 16) & 1u)) >> 16);
}
__device__ __forceinline__ float ldf(float v){ return v; }
__device__ __forceinline__ float ldf(ushort v){ return bf2f(v); }

// packed 2xf32 FMA (VOP3P) — compiler never auto-emits for scalar code
__device__ __forceinline__ f32x2 pk_fma(f32x2 a, f32x2 b, f32x2 c){
    f32x2 d;
    asm("v_pk_fma_f32 %0, %1, %2, %3" : "=v"(d) : "v"(a), "v"(b), "v"(c));
    return d;
}

// ---------------------------------------------------------------------------
// edge_index normalization: detect int32 vs int64 layout, clamp, write int32.
// ---------------------------------------------------------------------------
__global__ void idx_detect(const int* __restrict__ w, int* __restrict__ flag){
    __shared__ int sh[256];
    int t = threadIdx.x;
    int o = 0;
    for (int i = 2*t + 1; i < 2*E_EDGES; i += 512) o |= w[i];
    sh[t] = o; __syncthreads();
    for (int s = 128; s; s >>= 1){ if (t < s) sh[t] |= sh[t+s]; __syncthreads(); }
    if (t == 0) *flag = sh[0];
}

__global__ void idx_norm(const int* __restrict__ w, const int* __restrict__ flag,
                         int* __restrict__ srcN, int* __restrict__ dstN){
    int e = blockIdx.x*256 + threadIdx.x;
    if (e >= E_EDGES) return;
    int s, d;
    if (*flag){ s = w[e];     d = w[E_EDGES + e]; }          // int32 layout
    else      { s = w[2*e];   d = w[2*E_EDGES + 2*e]; }      // int64 layout (low words)
    s = min(max(s, 0), N_NODES-1);
    d = min(max(d, 0), N_NODES-1);
    srcN[e] = s; dstN[e] = d;
}

// ---------------------------------------------------------------------------
// pack_b: w2 [K][ROWS] f32 row-major -> per-wave-tile bf16 fragment layout.
// Tile ((kz*IP+ip)*CH+kc)*4 + wv is a contiguous 4 KB block; 16B unit
// (ns*64+lane) = w2[kcg*64+kg*32+q*8 .. +7][ip*128+ng*64+ns*16+ln], the exact
// MFMA B-fragment lane (q,ln) consumes.  Consecutive (ip,kc) tiles for a wave
// are a UNIFORM 16 KB apart (incl. the ip-wrap) -> single ptr-add per tile.
// ---------------------------------------------------------------------------
template<int K, int IP, int CH>
__global__ void pack_b(const float* __restrict__ w2, ushort* __restrict__ out){
    constexpr int ROWS = IP * 128;
    const int kcg = blockIdx.x;           // [0, K/64)
    const int rs  = blockIdx.y;           // [0, IP*2)
    const int t   = threadIdx.x;          // 256 threads, 2 units each
    const int ip  = rs >> 1, ng = rs & 1;
    const int kz  = kcg / CH, kc = kcg % CH;
    #pragma unroll
    for (int h = 0; h < 2; h++){
        int u512 = t + h * 256;
        int kg   = u512 >> 8;             // 0..1
        int u    = u512 & 255;            // unit within tile
        int ns   = u >> 6, lane = u & 63;
        int q    = lane >> 4, ln = lane & 15;
        int row   = ip * 128 + ng * 64 + ns * 16 + ln;
        int kbase = kcg * 64 + kg * 32 + q * 8;
        size_t tile = ((size_t)(kz * IP + ip) * CH + kc) * 4 + (kg * 2 + ng);
        ushort vv[8];
        #pragma unroll
        for (int j = 0; j < 8; j++)
            vv[j] = f2bf(w2[(size_t)(kbase + j) * ROWS + row]);
        *(uint4*)&out[tile * 2048 + (size_t)u * 8] = *(const uint4*)vv;
    }
}

// ---------------------------------------------------------------------------
// Fused per-edge-MLP GEMM + einsum + scatter-add.
//
// R10 (delete the zero-reuse B LDS staging — Common-mistake #7): each lane's
// B fragment is a contiguous 16B global chunk (verified identical to R4's
// writer/reader mapping), so the DMA->LDS->ds_read round-trip (32KB write +
// 32KB read per round of LDS-port time + the vmcnt->ds_read->lgkm chain) was
// pure overhead.  Now: pre-packed fragment-order B (pack_b) + direct
// global_load_dwordx4 into a register double-buffer (bA/bB, unroll-2 over kc,
// compile-time indices), perfectly coalesced (lane i at base+16i), one
// constant +16KB pointer add per tile, compiler-managed vmcnt.
// R4 otherwise retained: 64-edge blocks, kz=16, 16x16x32 MFMA, conflict-free
// A swizzle, pk-f32 h-scale + A-stage, b2 via LDS.
// ---------------------------------------------------------------------------
template<int K, int NI, int KS, typename TH>
__global__ __launch_bounds__(256, 2)
void gemm_msg(const float* __restrict__ ea4,
              const int* __restrict__ srcI, const int* __restrict__ dstI,
              const float* __restrict__ w1, const float* __restrict__ b1,
              const ushort* __restrict__ Bt, const float* __restrict__ b2,
              const TH* __restrict__ hsrc,
              float* __restrict__ nodesum)
{
    constexpr int CH = K / 64 / KS;   // K-chunks per block (A resident in regs), even
    constexpr int IP = NI / 2;        // i-pair passes (Ntile = 128)

    __shared__ __align__(16) ushort pool[16512];    // 33 KB: A-stage(<=32K) / mr+b2s(33K)
    __shared__ __align__(16) ushort h_s[NI][68];
    __shared__ float ea_s[256];
    __shared__ int src_s[64];
    __shared__ int dst_s[64];

    const int bid  = blockIdx.x;
    const int eb   = bid % NEB;
    const int kz   = bid / NEB;
    const int t    = threadIdx.x;
    const int e0   = eb * 64;
    const int lane = t & 63;
    const int wv   = t >> 6;
    const int ng   = wv & 1;
    const int kg   = wv >> 1;
    const int q    = lane >> 4;
    const int ln   = lane & 15;

    if (t < 64){ src_s[t] = srcI[e0 + t]; dst_s[t] = dstI[e0 + t]; }
    ea_s[t] = ea4[e0 * 4 + t];
    __syncthreads();

    // stage h_s[i][row]
    if (NI == 64){
        int r = t >> 2, ig = t & 3;
        const ushort* hp = (const ushort*)hsrc + (size_t)src_s[r] * 64 + ig * 16;
        uint4 v0 = *(const uint4*)(hp);
        uint4 v1 = *(const uint4*)(hp + 8);
        const ushort* p0 = (const ushort*)&v0;
        const ushort* p1 = (const ushort*)&v1;
        #pragma unroll
        for (int ii = 0; ii < 8; ii++) h_s[ig*16 + ii    ][r] = p0[ii];
        #pragma unroll
        for (int ii = 0; ii < 8; ii++) h_s[ig*16 + 8 + ii][r] = p1[ii];
    } else {
        if (t < 64){
            const TH* hp = hsrc + (size_t)src_s[t] * NI;
            #pragma unroll
            for (int ii = 0; ii < NI; ii++) h_s[ii][t] = f2bf(ldf(hp[ii]));
        }
    }

    // stage all CH A-chunks into pool (on-the-fly edge MLP layer 1, pk-f32), swizzled
    #pragma unroll 1
    for (int kc = 0; kc < CH; kc++){
        int kcg = kz * CH + kc;
        #pragma unroll
        for (int s2 = 0; s2 < 2; s2++){
            int a = t + s2 * 256;
            int r = a >> 3, oct = a & 7;
            int k = kcg * 64 + oct * 8;
            f32x2 a2[4];
            float4 b0 = *(const float4*)(b1 + k);
            float4 b4 = *(const float4*)(b1 + k + 4);
            a2[0] = f32x2{b0.x, b0.y}; a2[1] = f32x2{b0.z, b0.w};
            a2[2] = f32x2{b4.x, b4.y}; a2[3] = f32x2{b4.z, b4.w};
            #pragma unroll
            for (int a4 = 0; a4 < 4; a4++){
                float4 w0 = *(const float4*)(w1 + (size_t)a4 * K + k);
                float4 w4 = *(const float4*)(w1 + (size_t)a4 * K + k + 4);
                float m = ea_s[r * 4 + a4];
                f32x2 mm = {m, m};
                a2[0] = pk_fma(mm, f32x2{w0.x, w0.y}, a2[0]);
                a2[1] = pk_fma(mm, f32x2{w0.z, w0.w}, a2[1]);
                a2[2] = pk_fma(mm, f32x2{w4.x, w4.y}, a2[2]);
                a2[3] = pk_fma(mm, f32x2{w4.z, w4.w}, a2[3]);
            }
            uint4 ov;
            ushort* po = (ushort*)&ov;
            #pragma unroll
            for (int j = 0; j < 8; j++) po[j] = f2bf(fmaxf(a2[j >> 1][j & 1], 0.f));
            *(uint4*)&pool[kc * 4096 + r * 64 + ((oct ^ (r & 7)) * 8)] = ov;
        }
    }
    __syncthreads();

    // hoist ALL A fragments to registers: afA[kc][ms]
    const int j0 = kg * 4 + q;
    bf16x8v afA[CH][4];
    #pragma unroll
    for (int kc = 0; kc < CH; kc++)
        #pragma unroll
        for (int ms = 0; ms < 4; ms++){
            int r = ms * 16 + ln;
            afA[kc][ms] = *(const bf16x8v*)&pool[kc * 4096 + r * 64 + ((j0 ^ (r & 7)) * 8)];
        }
    __syncthreads();

    // B: direct fragment loads from packed layout; wave's tiles are contiguous
    // at uniform 16 KB stride.  gp0 = this wave's tile 0, pre-offset by lane.
    const ushort* gp0 = Bt + ((size_t)(kz * IP * CH) * 4 + wv) * 2048 + lane * 8;

    f32x2 msgp[4][4][2];
    #pragma unroll
    for (int a = 0; a < 4; a++)
        #pragma unroll
        for (int b = 0; b < 4; b++){
            msgp[a][b][0] = f32x2{0.f, 0.f};
            msgp[a][b][1] = f32x2{0.f, 0.f};
        }

    const f32x4 fzero = {0.f, 0.f, 0.f, 0.f};

    // register double-buffer; prologue: load tile (0,0) into bA
    bf16x8v bA[4], bB[4];
    #pragma unroll
    for (int ns = 0; ns < 4; ns++)
        bA[ns] = *(const bf16x8v*)(gp0 + ns * 512);
    gp0 += 8192;

    #pragma unroll 1
    for (int ip = 0; ip < IP; ip++){
        f32x4 acc[4][4];
        #pragma unroll
        for (int kc = 0; kc < CH; kc += 2){
            // even tile: prefetch (ip,kc+1) into bB (always a valid tile), MFMA bA
            #pragma unroll
            for (int ns = 0; ns < 4; ns++)
                bB[ns] = *(const bf16x8v*)(gp0 + ns * 512);
            gp0 += 8192;

            __builtin_amdgcn_s_setprio(1);
            #pragma unroll
            for (int ms = 0; ms < 4; ms++)
                #pragma unroll
                for (int ns = 0; ns < 4; ns++)
                    acc[ms][ns] = __builtin_amdgcn_mfma_f32_16x16x32_bf16(
                        afA[kc][ms], bA[ns], (kc == 0) ? fzero : acc[ms][ns], 0, 0, 0);
            __builtin_amdgcn_s_setprio(0);

            // odd tile: prefetch next pair's even tile into bA (guard only the
            // final pair of the final ip), MFMA bB
            if (kc + 2 < CH || ip < IP - 1){
                #pragma unroll
                for (int ns = 0; ns < 4; ns++)
                    bA[ns] = *(const bf16x8v*)(gp0 + ns * 512);
                gp0 += 8192;
            }

            __builtin_amdgcn_s_setprio(1);
            #pragma unroll
            for (int ms = 0; ms < 4; ms++)
                #pragma unroll
                for (int ns = 0; ns < 4; ns++)
                    acc[ms][ns] = __builtin_amdgcn_mfma_f32_16x16x32_bf16(
                        afA[kc + 1][ms], bB[ns], acc[ms][ns], 0, 0, 0);
            __builtin_amdgcn_s_setprio(0);
        }
        // h-scale epilogue (packed f32), once per i-pair
        int i2 = ip * 2 + ng;
        #pragma unroll
        for (int ms = 0; ms < 4; ms++){
            bf16x4v hb = *(const bf16x4v*)&h_s[i2][ms * 16 + q * 4];
            f32x2 h01, h23;
            h01[0] = bf2f((ushort)hb[0]); h01[1] = bf2f((ushort)hb[1]);
            h23[0] = bf2f((ushort)hb[2]); h23[1] = bf2f((ushort)hb[3]);
            #pragma unroll
            for (int ns = 0; ns < 4; ns++){
                f32x2 lo = __builtin_shufflevector(acc[ms][ns], acc[ms][ns], 0, 1);
                f32x2 hi = __builtin_shufflevector(acc[ms][ns], acc[ms][ns], 2, 3);
                msgp[ms][ns][0] = pk_fma(h01, lo, msgp[ms][ns][0]);
                msgp[ms][ns][1] = pk_fma(h23, hi, msgp[ms][ns][1]);
            }
        }
    }

    // reduce the 4 waves' msg partials in LDS (reuse pool), add b2 (kz==0), scatter
    __syncthreads();
    float* mr  = (float*)&pool[0];         // [64][65] f32 = 16,640 B
    float* b2s = (float*)&pool[0] + 4160;  // b2 staged: 16,384 B (ends 33,024 B = pool)
    if (kz == 0){
        for (int i = t; i < NI * 64; i += 256) b2s[i] = b2[i];
    }
    #pragma unroll 1
    for (int r4 = 0; r4 < 4; r4++){
        if (wv == r4){
            #pragma unroll
            for (int ms = 0; ms < 4; ms++)
                #pragma unroll
                for (int ns = 0; ns < 4; ns++)
                    #pragma unroll
                    for (int j = 0; j < 4; j++){
                        int row = ms * 16 + q * 4 + j, col = ns * 16 + ln;
                        float v = msgp[ms][ns][j >> 1][j & 1];
                        if (r4 == 0) mr[row * 65 + col]  = v;
                        else         mr[row * 65 + col] += v;
                    }
        }
        __syncthreads();
    }
    #pragma unroll 1
    for (int s2 = 0; s2 < 16; s2++){
        int a = t + s2 * 256;
        int row = a >> 6, o = a & 63;
        float v = mr[row * 65 + o];
        if (kz == 0){
            #pragma unroll 4
            for (int ii = 0; ii < NI; ii++)
                v += bf2f(h_s[ii][row]) * b2s[ii * 64 + o];
        }
        atomicAdd(nodesum + (size_t)dst_s[row] * 64 + o, v);
    }
}

// ---------------------------------------------------------------------------
__global__ void count_k(const int* __restrict__ dstI, float* __restrict__ cnt){
    int e = blockIdx.x * 256 + threadIdx.x;
    if (e < E_EDGES) atomicAdd(cnt + dstI[e], 1.f);
}

template<int NIn, typename TI>
__global__ void node_k(const float* __restrict__ ns_, const float* __restrict__ cnt,
                       const TI* __restrict__ xin, const float* __restrict__ root,
                       const float* __restrict__ bias,
                       ushort* __restrict__ hb, float* __restrict__ hf, int Nn)
{
    int idx = blockIdx.x * 256 + threadIdx.x;
    if (idx >= Nn * 64) return;
    int n = idx >> 6, o = idx & 63;
    float c = cnt[n];
    float inv = c > 1.f ? 1.f / c : 1.f;
    float s = ns_[idx] * inv + bias[o];
    #pragma unroll
    for (int i = 0; i < NIn; i++)
        s += ldf(xin[(size_t)n * NIn + i]) * root[i * 64 + o];
    s = fmaxf(s, 0.f);
    if (hb) hb[idx] = f2bf(s);
    else    hf[idx] = s;
}

// outputs FLOAT32: [E] prob | [E,3] types | [E] src | [E] dst
__global__ void edge_out_k(const float* __restrict__ h2, const int* __restrict__ srcI,
                           const int* __restrict__ dstI, const float* __restrict__ ea,
                           const float* __restrict__ fcw, const float* __restrict__ fcb,
                           float* __restrict__ out)
{
    __shared__ float fw[396];
    __shared__ float fb[3];
    int t = threadIdx.x;
    for (int i = t; i < 396; i += 256) fw[i] = fcw[i];
    if (t < 3) fb[t] = fcb[t];
    __syncthreads();
    int e = blockIdx.x * 256 + t;
    int s = srcI[e], d = dstI[e];
    const float* hs = h2 + (size_t)s * 64;
    const float* hd = h2 + (size_t)d * 64;
    float dot = 0.f, l0 = fb[0], l1 = fb[1], l2 = fb[2];
    #pragma unroll 8
    for (int c = 0; c < 64; c++){
        float a = hs[c], b = hd[c];
        dot += a * b;
        l0 += a * fw[c*3+0] + b * fw[(64+c)*3+0];
        l1 += a * fw[c*3+1] + b * fw[(64+c)*3+1];
        l2 += a * fw[c*3+2] + b * fw[(64+c)*3+2];
    }
    #pragma unroll
    for (int a4 = 0; a4 < 4; a4++){
        float v = ea[e*4 + a4];
        l0 += v * fw[(128+a4)*3+0];
        l1 += v * fw[(128+a4)*3+1];
        l2 += v * fw[(128+a4)*3+2];
    }
    float prob = 1.f / (1.f + __expf(-dot));
    float m  = fmaxf(l0, fmaxf(l1, l2));
    float x0 = __expf(l0 - m), x1 = __expf(l1 - m), x2 = __expf(l2 - m);
    float inv = 1.f / (x0 + x1 + x2);
    out[e]                  = prob;
    out[E_EDGES + 3*e + 0]  = x0 * inv;
    out[E_EDGES + 3*e + 1]  = x1 * inv;
    out[E_EDGES + 3*e + 2]  = x2 * inv;
    out[4*E_EDGES + e]      = (float)s;
    out[5*E_EDGES + e]      = (float)d;
}

// ---------------------------------------------------------------------------
extern "C" void kernel_launch(void* const* d_in, const int* in_sizes, int n_in,
                              void* d_out, int out_size, void* d_ws, size_t ws_size,
                              hipStream_t stream)
{
    const float* x     = (const float*)d_in[0];
    const int*   ei    = (const int*)  d_in[1];
    const float* ea    = (const float*)d_in[2];
    const float* e1w1  = (const float*)d_in[3];
    const float* e1b1  = (const float*)d_in[4];
    const float* e1w2  = (const float*)d_in[5];
    const float* e1b2  = (const float*)d_in[6];
    const float* root1 = (const float*)d_in[7];
    const float* bias1 = (const float*)d_in[8];
    const float* e2w1  = (const float*)d_in[9];
    const float* e2b1  = (const float*)d_in[10];
    const float* e2w2  = (const float*)d_in[11];
    const float* e2b2  = (const float*)d_in[12];
    const float* root2 = (const float*)d_in[13];
    const float* bias2 = (const float*)d_in[14];
    const float* fcw   = (const float*)d_in[15];
    const float* fcb   = (const float*)d_in[16];

    char* ws = (char*)d_ws;
    float*  ns1  = (float*) (ws + 0);          // [N,64] f32   2,560,000 B
    float*  ns2  = (float*) (ws + 2560000);    // [N,64] f32   2,560,000 B
    float*  cnt  = (float*) (ws + 5120000);    // [N] f32         40,000 B
    int*    flag = (int*)   (ws + 5160000);    // 4 B (+pad)
    int*    srcN = (int*)   (ws + 5160064);    // [E] int32     131,072 B
    int*    dstN = (int*)   (ws + 5291136);    // [E] int32     131,072 B
    ushort* h1   = (ushort*)(ws + 5422208);    // [N,64] bf16 1,280,000 B
    float*  h2   = (float*) (ws + 6702208);    // [N,64] f32  2,560,000 B
    ushort* B1t  = (ushort*)(ws + 9262208);    // packed e1w2 bf16 (294,912 B)
    ushort* B2t  = (ushort*)(ws + 9557120);    // packed e2w2 bf16 (64 MB) -> ends 43,111,552

    hipMemsetAsync(d_ws, 0, 5160064, stream);   // zero ns1, ns2, cnt, flag

    idx_detect<<<1, 256, 0, stream>>>(ei, flag);
    idx_norm<<<128, 256, 0, stream>>>(ei, flag, srcN, dstN);

    // pack B matrices into per-wave-tile fragment order
    // conv1: K=384, IP=3, CH=2  -> grid (6, 6)
    pack_b<384, 3, 2><<<dim3(6, 6), 256, 0, stream>>>(e1w2, B1t);
    // conv2: K=4096, IP=32, CH=4 -> grid (64, 64)
    pack_b<4096, 32, 4><<<dim3(64, 64), 256, 0, stream>>>(e2w2, B2t);
    count_k<<<128, 256, 0, stream>>>(dstN, cnt);

    // small conv1: K=384, KS=3 -> CH=2, IP=3, kz=3
    gemm_msg<384, 6, 3, float><<<NEB*3, 256, 0, stream>>>(ea, srcN, dstN, e1w1, e1b1, B1t, e1b2, x, ns1);
    node_k<6, float><<<2500, 256, 0, stream>>>(ns1, cnt, x, root1, bias1, h1, nullptr, N_NODES);

    // big conv2: K=4096, KS=16 -> CH=4, IP=32, kz=16 (direct-reg B, no LDS staging)
    gemm_msg<4096, 64, 16, ushort><<<NEB*16, 256, 0, stream>>>(ea, srcN, dstN, e2w1, e2b1, B2t, e2b2, h1, ns2);
    node_k<64, ushort><<<2500, 256, 0, stream>>>(ns2, cnt, h1, root2, bias2, nullptr, h2, N_NODES);

    edge_out_k<<<128, 256, 0, stream>>>(h2, srcN, dstN, ea, fcw, fcb, (float*)d_out);
}